// Round 10
// baseline (163.548 us; speedup 1.0000x reference)
//
#include <hip/hip_runtime.h>
#include <cfloat>

// Emu3 VQ-VAE vector quantizer argmin (exact-rounding match to numpy ref):
//   x [9216,4] f32 (channels-last gather from [1,4,4,48,48])
//   e [32768,4] f32
//   out[n] = argmin_k fl( fl(x2+e2) - 2*fl(dot) ), first-min tie semantics.
//
// Round 10: persistent-block LDS design. R1-R9 falsified VALU / occupancy /
// L2-pattern / traffic / spill theories; surviving model is per-iteration
// loaded-latency gating of the global K-loop (64 iters x ~3K cyc = 200K cyc
// for EVERY config). Here: grid 256 = 1 block/CU, 36 rows/block, codebook in
// 32 double-buffered LDS slabs (1024 entries, global_load_lds w=16, R2-
// verified); each stage hides under a full slab of LDS-resident compute.
// Traffic 128 MB (4x under R9). Rows' x in LDS (float4 + x2), broadcast-read
// per 12-row chunk; best/bidx[36] in regs under launch_bounds(512,2) cap 256.
// Math chain / strict-< ascending scan / 32-bit shfl reduce: verified.

#define BLOCK  512
#define ROWS   36
#define RC     12                 // rows per register chunk
#define NCH    (ROWS / RC)        // 3
#define SLAB   1024               // entries per LDS slab (16 KB)
#define NSLAB  (32768 / SLAB)     // 32
#define EPT    (SLAB / BLOCK)     // 2 entries per thread per slab

typedef const __attribute__((address_space(1))) void GAS;
typedef __attribute__((address_space(3))) void LAS;

__global__ __launch_bounds__(BLOCK, 2)
void vq_argmin_kernel(const float* __restrict__ hs,
                      const float4* __restrict__ cb,
                      int* __restrict__ out)
{
    __shared__ float4 buf[2][SLAB];      // 32 KB double-buffered slab
    __shared__ float4 sX4[ROWS];         // per-row x components
    __shared__ float  sX1[ROWS];         // per-row ||x||^2

    const int tid = threadIdx.x;
    const int rowbase = blockIdx.x * ROWS;

    // ---- stage slab 0 immediately (async; drained by the first barrier)
    #pragma unroll
    for (int j = 0; j < EPT; ++j) {
        int slot = j * BLOCK + tid;
        __builtin_amdgcn_global_load_lds((GAS*)(cb + slot),
                                         (LAS*)(&buf[0][slot]), 16, 0, 0);
    }

    // ---- stage row x-data into LDS (threads 0..35), exact x2 chain
    if (tid < ROWS) {
        int n = rowbase + tid;
        int t = n / 2304;                 // 2304 = 48*48
        int rem = n - t * 2304;
        const float* p = hs + t * 9216 + rem;   // + c*2304 per channel
        float a0 = p[0], a1 = p[2304], a2 = p[4608], a3 = p[6912];
        sX4[tid] = make_float4(a0, a1, a2, a3);
        sX1[tid] = __fadd_rn(__fadd_rn(__fadd_rn(__fmul_rn(a0, a0),
                                                 __fmul_rn(a1, a1)),
                                       __fmul_rn(a2, a2)),
                             __fmul_rn(a3, a3));
    }

    float best[ROWS];
    int   bidx[ROWS];
    #pragma unroll
    for (int r = 0; r < ROWS; ++r) { best[r] = FLT_MAX; bidx[r] = 0; }

    // ---- K loop over LDS slabs: stage s+1 async while computing s
    for (int s = 0; s < NSLAB; ++s) {
        __syncthreads();   // drains vmcnt -> buf[s&1] ready; x-data ready (s=0)
        if (s + 1 < NSLAB) {
            const float4* src = cb + (s + 1) * SLAB;
            #pragma unroll
            for (int j = 0; j < EPT; ++j) {
                int slot = j * BLOCK + tid;
                __builtin_amdgcn_global_load_lds((GAS*)(src + slot),
                                                 (LAS*)(&buf[(s + 1) & 1][slot]),
                                                 16, 0, 0);
            }
        }
        const float4* sb = buf[s & 1];
        int kbase = s * SLAB + tid;
        #pragma unroll
        for (int c = 0; c < NCH; ++c) {
            // broadcast-load this chunk's 12 rows into registers
            float4 xr[RC]; float xq[RC];
            #pragma unroll
            for (int r = 0; r < RC; ++r) {
                xr[r] = sX4[c * RC + r];
                xq[r] = sX1[c * RC + r];
            }
            #pragma unroll
            for (int j = 0; j < EPT; ++j) {
                float4 e = sb[j * BLOCK + tid];
                float e2 = __fadd_rn(__fadd_rn(__fadd_rn(__fmul_rn(e.x, e.x),
                                                         __fmul_rn(e.y, e.y)),
                                               __fmul_rn(e.z, e.z)),
                                     __fmul_rn(e.w, e.w));
                int kk = kbase + j * BLOCK;
                #pragma unroll
                for (int r = 0; r < RC; ++r) {
                    float dot = __builtin_fmaf(xr[r].w, e.w,
                                __builtin_fmaf(xr[r].z, e.z,
                                __builtin_fmaf(xr[r].y, e.y,
                                __fmul_rn(xr[r].x, e.x))));
                    float t1 = __fadd_rn(xq[r], e2);
                    float d  = __builtin_fmaf(dot, -2.0f, t1);
                    int idx = c * RC + r;
                    if (d < best[idx]) { best[idx] = d; bidx[idx] = kk; }
                }
            }
        }
    }

    // ---- wave-level lexicographic (dist, idx) butterfly reduction
    #pragma unroll
    for (int r = 0; r < ROWS; ++r) {
        float d = best[r]; int i = bidx[r];
        #pragma unroll
        for (int off = 32; off >= 1; off >>= 1) {
            float d2 = __shfl_xor(d, off, 64);
            int   i2 = __shfl_xor(i, off, 64);
            if (d2 < d || (d2 == d && i2 < i)) { d = d2; i = i2; }
        }
        best[r] = d; bidx[r] = i;
    }

    // ---- cross-wave reduce via scratch aliased into the slab buffer
    __syncthreads();                       // all compute done; buf reusable
    float* rd = (float*)&buf[0][0];        // 8 waves x 36 dists
    int*   ri = (int*)(rd + 8 * ROWS);     // 8 waves x 36 indices

    int wave = tid >> 6;
    if ((tid & 63) == 0) {
        #pragma unroll
        for (int r = 0; r < ROWS; ++r) {
            rd[wave * ROWS + r] = best[r];
            ri[wave * ROWS + r] = bidx[r];
        }
    }
    __syncthreads();

    if (tid < ROWS) {
        float d = rd[tid]; int i = ri[tid];
        #pragma unroll
        for (int w = 1; w < 8; ++w) {
            float d2 = rd[w * ROWS + tid];
            int   i2 = ri[w * ROWS + tid];
            if (d2 < d || (d2 == d && i2 < i)) { d = d2; i = i2; }
        }
        out[rowbase + tid] = i;
    }
}

extern "C" void kernel_launch(void* const* d_in, const int* in_sizes, int n_in,
                              void* d_out, int out_size, void* d_ws, size_t ws_size,
                              hipStream_t stream)
{
    const float*  hs = (const float*)d_in[0];    // [1,4,4,48,48]
    const float4* cb = (const float4*)d_in[1];   // [32768,4]
    int* out = (int*)d_out;                      // [9216] int32

    dim3 grid(9216 / ROWS), block(BLOCK);        // 256 blocks = 1/CU
    vq_argmin_kernel<<<grid, block, 0, stream>>>(hs, cb, out);
}